// Round 4
// baseline (723.084 us; speedup 1.0000x reference)
//
#include <hip/hip_runtime.h>

typedef __attribute__((ext_vector_type(8))) short short8;
typedef __attribute__((ext_vector_type(4))) float f32x4;

__device__ __forceinline__ unsigned short f2b(float f){
  union { float f; unsigned u; } x; x.f = f;
  unsigned r = x.u + 0x7fffu + ((x.u >> 16) & 1u);
  return (unsigned short)(r >> 16);
}
__device__ __forceinline__ float b2f(unsigned short v){
  union { unsigned u; float f; } x; x.u = ((unsigned)v) << 16; return x.f;
}

#define GATE4() asm volatile("s_waitcnt vmcnt(4)" ::: "memory")
#define GATE0() asm volatile("s_waitcnt vmcnt(0)" ::: "memory")
#define LGK()   asm volatile("s_waitcnt lgkmcnt(0)" ::: "memory")
#define BAR()   __builtin_amdgcn_s_barrier()
#define SCHED() __builtin_amdgcn_sched_barrier(0)

// raw LDS read, invisible to the compiler's LDS-DMA alias analysis
// (prevents auto-inserted s_waitcnt vmcnt(0) before each phase's ds_reads)
__device__ __forceinline__ short8 DSR(unsigned off){
  short8 r;
  asm volatile("ds_read_b128 %0, %1" : "=v"(r) : "v"(off));
  return r;
}

// ---------------- CSR build ----------------
__global__ void count_k(const int* __restrict__ dst, int* __restrict__ deg, int E){
  int e = blockIdx.x*256 + threadIdx.x;
  if (e < E) atomicAdd(&deg[dst[e]], 1);
}

__global__ void scan_k(const int* __restrict__ deg, int* __restrict__ rowstart,
                       int* __restrict__ cursor, int n)
{
  __shared__ int wsum[16];
  __shared__ int carry_s;
  int tid = threadIdx.x, lane = tid & 63, wv = tid >> 6;
  if (tid == 0) carry_s = 0;
  __syncthreads();
  for (int base = 0; base < n; base += 1024){
    int i = base + tid;
    int v = (i < n) ? deg[i] : 0;
    int xv = v;
    #pragma unroll
    for (int o=1;o<64;o<<=1){ int t = __shfl_up(xv, o, 64); if (lane >= o) xv += t; }
    if (lane == 63) wsum[wv] = xv;
    __syncthreads();
    if (tid < 16){
      int w = wsum[tid];
      #pragma unroll
      for (int o=1;o<16;o<<=1){ int t = __shfl_up(w, o, 64); if (tid >= o) w += t; }
      wsum[tid] = w;
    }
    __syncthreads();
    int woff = (wv == 0) ? 0 : wsum[wv-1];
    int carry = carry_s;
    if (i < n){ int excl = carry + woff + xv - v; rowstart[i] = excl; cursor[i] = excl; }
    int total = wsum[15];
    __syncthreads();
    if (tid == 0) carry_s = carry + total;
    __syncthreads();
  }
  if (threadIdx.x == 0) rowstart[n] = carry_s;
}

__global__ void fill_k(const int* __restrict__ src, const int* __restrict__ dst,
                       int* __restrict__ cursor, int* __restrict__ csrc, int E){
  int e = blockIdx.x*256 + threadIdx.x;
  if (e < E){
    int p = atomicAdd(&cursor[dst[e]], 1);
    csrc[p] = src[e];
  }
}

// ---------------- weight transpose + bf16 convert: Wt[o][i] = W[i][o] ----------------
__global__ void transpose_k(const float* __restrict__ W, unsigned short* __restrict__ Wt,
                            int r, int c){
  int idx = blockIdx.x*256 + threadIdx.x;
  int total = c * (r >> 3);
  if (idx >= total) return;
  int o = idx % c;
  int i0 = (idx / c) << 3;
  short8 vv;
  #pragma unroll
  for (int j=0;j<8;j++) ((unsigned short*)&vv)[j] = f2b(W[(size_t)(i0+j)*c + o]);
  *(short8*)&Wt[(size_t)o*r + i0] = vv;
}

// ---------------- f32 -> bf16 convert ----------------
__global__ void cvt_k(const float* __restrict__ in, unsigned short* __restrict__ out, size_t n){
  size_t i = ((size_t)blockIdx.x*256 + threadIdx.x)*8;
  if (i >= n) return;
  const float4* p = (const float4*)(in + i);
  float4 a0 = p[0], a1 = p[1];
  short8 vv;
  ((unsigned short*)&vv)[0] = f2b(a0.x); ((unsigned short*)&vv)[1] = f2b(a0.y);
  ((unsigned short*)&vv)[2] = f2b(a0.z); ((unsigned short*)&vv)[3] = f2b(a0.w);
  ((unsigned short*)&vv)[4] = f2b(a1.x); ((unsigned short*)&vv)[5] = f2b(a1.y);
  ((unsigned short*)&vv)[6] = f2b(a1.z); ((unsigned short*)&vv)[7] = f2b(a1.w);
  *(short8*)&out[i] = vv;
}

// ---------------- 256x256x64 8-phase GEMM (T2+T3+T4+T5), 8 waves ----------------
// A[M][KC] bf16, Bt[NBLK*256][KC] bf16.
// MODE 0: QKVS  (bias split; col<1536 -> bf16 outB[row][1536], else bf16 outB2[row][512])
// MODE 1: FFN1  (bias + relu -> bf16 outB[row][NBLK*256])
// MODE 2: FFN2  (bias + res  -> f32 outF[row][512])
template<int MODE, int KC, int NBLK>
__global__ __launch_bounds__(512, 2) void gemm8_k(
    const unsigned short* __restrict__ A,
    const unsigned short* __restrict__ Bt,
    int M,
    const float* __restrict__ bias0, const float* __restrict__ bias1,
    const float* __restrict__ bias2, const float* __restrict__ bias3,
    unsigned short* __restrict__ outB, unsigned short* __restrict__ outB2,
    float* __restrict__ outF, const float* __restrict__ res)
{
  // single LDS pool (shorts): lA buf0 [0,16384) buf1 [16384,32768)
  //                           lB buf0 [32768,49152) buf1 [49152,65536)
  __shared__ unsigned short LDS[65536];
  const int tid  = threadIdx.x;
  const int lane = tid & 63;
  const int wid  = tid >> 6;
  const int wm   = wid >> 2;      // 0..1  -> 128-row slab
  const int wn   = wid & 3;       // 0..3  -> 64-col slab
  const int Mm1  = M - 1;

  // bijective XCD-chunked swizzle (m204)
  const int nwg = gridDim.x;
  int id = blockIdx.x;
  int q = nwg >> 3, r = nwg & 7;
  int xc = id & 7, yy = id >> 3;
  int swz = (xc < r ? xc*(q+1) : r*(q+1) + (xc-r)*q) + yy;
  const int bm = (swz / NBLK) * 256;
  const int bn = (swz % NBLK) * 256;

  f32x4 acc[8][4];
  #pragma unroll
  for (int m=0;m<8;m++)
    #pragma unroll
    for (int n=0;n<4;n++) acc[m][n] = (f32x4)0.f;

  // LDS byte addressing (low 32 bits of generic shared ptr = LDS offset)
  const unsigned B0 = (unsigned)(size_t)(const void*)(&LDS[0]);
  const unsigned c0 = 2u * (((lane >> 4) ^ (lane & 7)) * 8);
  const unsigned c1 = 2u * (((4 + (lane >> 4)) ^ (lane & 7)) * 8);
  const unsigned aA = B0 + 2u * ((wm*128 + (lane & 15)) * 64);
  const unsigned aB = B0 + 2u * (32768 + (wn*64 + (lane & 15)) * 64);

  // stage one 128x64 half-tile (2 global_load_lds per wave), linear dest,
  // source pre-swizzled (rule 21)
  auto ST_A = [&](int buf, int half, int kt){
    #pragma unroll
    for (int it=0; it<2; ++it){
      int rt = half*128 + it*64 + (tid >> 3);
      int scol = ((tid & 7) ^ (rt & 7)) * 8;
      int gr = bm + rt; if (gr > Mm1) gr = Mm1;
      __builtin_amdgcn_global_load_lds(
        (const __attribute__((address_space(1))) void*)(A + (size_t)gr*KC + kt + scol),
        (__attribute__((address_space(3))) void*)(LDS + buf*16384 + half*8192 + it*4096 + wid*512),
        16, 0, 0);
    }
  };
  auto ST_B = [&](int buf, int half, int kt){
    #pragma unroll
    for (int it=0; it<2; ++it){
      int rt = half*128 + it*64 + (tid >> 3);
      int scol = ((tid & 7) ^ (rt & 7)) * 8;
      __builtin_amdgcn_global_load_lds(
        (const __attribute__((address_space(1))) void*)(Bt + (size_t)(bn + rt)*KC + kt + scol),
        (__attribute__((address_space(3))) void*)(LDS + 32768 + buf*16384 + half*8192 + it*4096 + wid*512),
        16, 0, 0);
    }
  };

  auto DS_A = [&](int buf, int P, short8* af){
    unsigned b = aA + (unsigned)buf*32768u + (unsigned)P*4096u;
    af[0] = DSR(b + c0);
    af[1] = DSR(b + c1);
    af[2] = DSR(b + 2048u + c0);
    af[3] = DSR(b + 2048u + c1);
  };
  auto DS_B = [&](int buf, short8 bfr[4][2]){
    unsigned b = aB + (unsigned)buf*32768u;
    #pragma unroll
    for (int g=0; g<4; ++g){
      bfr[g][0] = DSR(b + (unsigned)g*2048u + c0);
      bfr[g][1] = DSR(b + (unsigned)g*2048u + c1);
    }
  };
  auto MM = [&](int P, short8* af, short8 bfr[4][2]){
    __builtin_amdgcn_s_setprio(1);
    #pragma unroll
    for (int j=0;j<2;j++)
      #pragma unroll
      for (int g=0; g<4; g++){
        acc[2*P+j][g] = __builtin_amdgcn_mfma_f32_16x16x32_bf16(af[2*j],   bfr[g][0], acc[2*P+j][g], 0,0,0);
        acc[2*P+j][g] = __builtin_amdgcn_mfma_f32_16x16x32_bf16(af[2*j+1], bfr[g][1], acc[2*P+j][g], 0,0,0);
      }
    __builtin_amdgcn_s_setprio(0);
  };

  constexpr int NT = KC/64;
  constexpr int NI = NT/2;

  // prologue: K-tile0 -> buf0 (all), K-tile1 B -> buf1
  ST_A(0,0,0); ST_A(0,1,0); ST_B(0,0,0); ST_B(0,1,0);
  ST_B(1,0,64); ST_B(1,1,64);
  GATE4(); BAR();

  for (int i=0; i<NI; ++i){
    const int kt0 = i*128;
    const bool last = (i == NI-1);
    short8 af[4]; short8 bfr[4][2];
    // ---- phase 0 (buf0) ----
    DS_B(0, bfr); DS_A(0, 0, af);
    ST_A(1,0,kt0+64); ST_A(1,1,kt0+64);          // K-tile 2i+1 A -> buf1
    BAR(); LGK(); SCHED();
    MM(0, af, bfr); BAR();
    // ---- phase 1 ----
    DS_A(0, 1, af);
    if (!last) ST_B(0,0,kt0+128);                // K-tile 2i+2 B0 -> buf0
    BAR(); LGK(); SCHED(); MM(1, af, bfr); BAR();
    // ---- phase 2 ----
    DS_A(0, 2, af);
    if (!last) ST_B(0,1,kt0+128);
    BAR(); LGK(); SCHED(); MM(2, af, bfr); BAR();
    // ---- phase 3 (gate: buf1 K-tile must be resident) ----
    DS_A(0, 3, af);
    BAR(); LGK(); SCHED(); MM(3, af, bfr);
    if (!last) GATE4(); else GATE0();
    BAR();
    // ---- phase 4 (buf1) ----
    DS_B(1, bfr); DS_A(1, 0, af);
    if (!last) ST_A(0,0,kt0+128);                // K-tile 2i+2 A0 -> buf0
    BAR(); LGK(); SCHED(); MM(0, af, bfr); BAR();
    // ---- phase 5 ----
    DS_A(1, 1, af);
    if (!last) ST_A(0,1,kt0+128);
    BAR(); LGK(); SCHED(); MM(1, af, bfr); BAR();
    // ---- phase 6 ----
    DS_A(1, 2, af);
    if (!last) ST_B(1,0,kt0+192);                // K-tile 2i+3 B -> buf1
    BAR(); LGK(); SCHED(); MM(2, af, bfr); BAR();
    // ---- phase 7 (gate: buf0 next K-tile resident) ----
    DS_A(1, 3, af);
    if (!last) ST_B(1,1,kt0+192);
    BAR(); LGK(); SCHED(); MM(3, af, bfr);
    if (!last) GATE4();
    BAR();
  }

  // epilogue (bias hoisted: 4 cols per thread)
  #pragma unroll
  for (int g=0; g<4; ++g){
    int col = bn + wn*64 + g*16 + (lane & 15);
    float bval;
    if (MODE == 0){
      bval = (col < 512) ? bias0[col]
           : (col < 1024) ? bias1[col-512]
           : (col < 1536) ? bias2[col-1024] : bias3[col-1536];
    } else {
      bval = bias0[col];
    }
    #pragma unroll
    for (int f=0; f<8; ++f){
      int row0 = bm + wm*128 + f*16 + ((lane >> 4) << 2);
      #pragma unroll
      for (int r4=0;r4<4;r4++){
        int row = row0 + r4;
        if (row < M){
          float v = acc[f][g][r4] + bval;
          if (MODE == 0){
            if (col < 1536) outB[(size_t)row*1536 + col] = f2b(v);
            else            outB2[(size_t)row*512 + (col - 1536)] = f2b(v);
          } else if (MODE == 1){
            v = fmaxf(v, 0.0f);
            outB[(size_t)row*(NBLK*256) + col] = f2b(v);
          } else {
            v += res[(size_t)row*512 + col];
            outF[(size_t)row*512 + col] = v;
          }
        }
      }
    }
  }
}

// ---------------- attention: one wave per destination node, online softmax ----------------
__global__ __launch_bounds__(256) void attn_k(
  const unsigned short* __restrict__ qkv, const unsigned short* __restrict__ skipb,
  const float* __restrict__ enc, const int* __restrict__ rowstart,
  const int* __restrict__ csrc, float* __restrict__ xout,
  unsigned short* __restrict__ xoutb, int N)
{
  int n = blockIdx.x*4 + (threadIdx.x>>6);
  if (n >= N) return;
  int lane = threadIdx.x & 63;
  const short8 qv = *(const short8*)&qkv[(size_t)n*1536 + lane*8];
  float qf[8];
  #pragma unroll
  for (int j=0;j<8;j++) qf[j] = b2f(((const unsigned short*)&qv)[j]);
  float m = -__builtin_inff(), l = 0.f;
  float acc[8] = {0.f,0.f,0.f,0.f,0.f,0.f,0.f,0.f};
  int e = rowstart[n], e1 = rowstart[n+1];
  for (; e < e1; ++e){
    int s = csrc[e];
    const short8 kv = *(const short8*)&qkv[(size_t)s*1536 + 512 + lane*8];
    float dot = 0.f;
    #pragma unroll
    for (int j=0;j<8;j++) dot += qf[j]*b2f(((const unsigned short*)&kv)[j]);
    dot += __shfl_xor(dot,1); dot += __shfl_xor(dot,2); dot += __shfl_xor(dot,4);
    float a = dot * 0.125f;               // 1/sqrt(64)
    float mn = fmaxf(m, a);
    float corr = __expf(m - mn);
    float p = __expf(a - mn);
    l = l*corr + p;
    const short8 vv = *(const short8*)&qkv[(size_t)s*1536 + 1024 + lane*8];
    #pragma unroll
    for (int j=0;j<8;j++) acc[j] = acc[j]*corr + p*b2f(((const unsigned short*)&vv)[j]);
    m = mn;
  }
  float inv = 1.f/(l + 1e-16f);
  size_t base = (size_t)n*512 + (size_t)lane*8;
  const short8 sv = *(const short8*)&skipb[base];
  short8 ob;
  #pragma unroll
  for (int j=0;j<8;j++){
    float o = acc[j]*inv + b2f(((const unsigned short*)&sv)[j]) + enc[base+j];
    xout[base+j] = o;
    ((unsigned short*)&ob)[j] = f2b(o);
  }
  *(short8*)&xoutb[base] = ob;
}

// ---------------- LayerNorm (wave per row) ----------------
template<int MODE>
__global__ __launch_bounds__(256) void ln_k(const float* __restrict__ x,
  const float* __restrict__ g, const float* __restrict__ b,
  float* __restrict__ outF, unsigned short* __restrict__ outB,
  const float* __restrict__ addv, int N)
{
  int n = blockIdx.x*4 + (threadIdx.x>>6);
  if (n >= N) return;
  int lane = threadIdx.x & 63;
  size_t base = (size_t)n*512 + (size_t)lane*8;
  const float4* p = (const float4*)(x + base);
  float4 a0 = p[0], a1 = p[1];
  float v[8] = {a0.x,a0.y,a0.z,a0.w,a1.x,a1.y,a1.z,a1.w};
  float s=0.f, ss=0.f;
  #pragma unroll
  for (int j=0;j<8;j++){ s += v[j]; ss += v[j]*v[j]; }
  #pragma unroll
  for (int o=1;o<64;o<<=1){ s += __shfl_xor(s,o); ss += __shfl_xor(ss,o); }
  float mean = s * (1.f/512.f);
  float var  = ss * (1.f/512.f) - mean*mean;
  float rstd = rsqrtf(var + 1e-5f);
  #pragma unroll
  for (int j=0;j<8;j++){
    int c = lane*8 + j;
    float o = (v[j]-mean)*rstd*g[c] + b[c];
    if (MODE == 0){ outF[base+j] = o; outB[base+j] = f2b(o); }
    else          { outF[base+j] = o + addv[base+j]; }
  }
}

extern "C" void kernel_launch(void* const* d_in, const int* in_sizes, int n_in,
                              void* d_out, int out_size, void* d_ws, size_t ws_size,
                              hipStream_t stream)
{
  const float* x0  = (const float*)d_in[0];
  const int*  eidx = (const int*)d_in[1];
  const float* Wq  = (const float*)d_in[4];
  const float* bq  = (const float*)d_in[5];
  const float* Wk  = (const float*)d_in[6];
  const float* bk  = (const float*)d_in[7];
  const float* Wv  = (const float*)d_in[8];
  const float* bv  = (const float*)d_in[9];
  const float* Wsk = (const float*)d_in[10];
  const float* bs  = (const float*)d_in[11];
  const float* W1  = (const float*)d_in[12];
  const float* b1  = (const float*)d_in[13];
  const float* W2  = (const float*)d_in[14];
  const float* b2  = (const float*)d_in[15];
  const float* lng = (const float*)d_in[16];
  const float* lnb = (const float*)d_in[17];

  const int N = in_sizes[0] / 512;
  const int E = in_sizes[1] / 2;
  const int* esrc = eidx;
  const int* edst = eidx + E;

  char* ws = (char*)d_ws;
  size_t off = 0;
  auto alloc = [&](size_t bytes)->char*{
    char* p = ws + off; off = (off + bytes + 255) & ~(size_t)255; return p;
  };
  unsigned short* wtqkvs = (unsigned short*)alloc((size_t)2*2048*512*2);
  unsigned short* wt1    = (unsigned short*)alloc((size_t)1024*512*2);
  unsigned short* wt2    = (unsigned short*)alloc((size_t)512*1024*2);
  unsigned short* qkv    = (unsigned short*)alloc((size_t)N*1536*2);
  float*          skip   = (float*)alloc((size_t)N*512*4);   // f32 h after LN1
  float*          xbuf   = (float*)alloc((size_t)N*512*4);
  unsigned short* xb     = (unsigned short*)alloc((size_t)N*512*2); // bf16 x / hb
  unsigned short* skipb  = (unsigned short*)alloc((size_t)N*512*2); // bf16 skip proj
  int* deg      = (int*)alloc((size_t)N*4);
  int* rowstart = (int*)alloc((size_t)(N+1)*4);
  int* cursor   = (int*)alloc((size_t)N*4);
  int* csrc     = (int*)alloc((size_t)E*4);
  unsigned short* tbuf = qkv;  // alias: qkv dead by FFN time

  // CSR build
  hipMemsetAsync(deg, 0, (size_t)N*4, stream);
  count_k<<<(E+255)/256, 256, 0, stream>>>(edst, deg, E);
  scan_k<<<1, 1024, 0, stream>>>(deg, rowstart, cursor, N);
  fill_k<<<(E+255)/256, 256, 0, stream>>>(esrc, edst, cursor, csrc, E);

  // weight transposes (Wt[o][i] = W[i][o], bf16)
  for (int l = 0; l < 2; ++l){
    unsigned short* base = wtqkvs + (size_t)l*2048*512;
    transpose_k<<<(512*64+255)/256, 256, 0, stream>>>(Wq  + (size_t)l*512*512, base,            512, 512);
    transpose_k<<<(512*64+255)/256, 256, 0, stream>>>(Wk  + (size_t)l*512*512, base +  512*512, 512, 512);
    transpose_k<<<(512*64+255)/256, 256, 0, stream>>>(Wv  + (size_t)l*512*512, base + 1024*512, 512, 512);
    transpose_k<<<(512*64+255)/256, 256, 0, stream>>>(Wsk + (size_t)l*512*512, base + 1536*512, 512, 512);
  }
  transpose_k<<<(1024*64+255)/256, 256, 0, stream>>>(W1, wt1, 512, 1024);
  transpose_k<<<(512*128+255)/256, 256, 0, stream>>>(W2, wt2, 1024, 512);

  const int cvtBlocks = (int)(((size_t)N*512/8 + 255)/256);
  const int rowBlocks = (N + 3)/4;
  const int MB = (N + 255)/256;   // 79

  // 2 TransformerConv layers
  cvt_k<<<cvtBlocks, 256, 0, stream>>>(x0, xb, (size_t)N*512);
  for (int l = 0; l < 2; ++l){
    gemm8_k<0,512,8><<<MB*8, 512, 0, stream>>>(xb, wtqkvs + (size_t)l*2048*512, N,
        bq + l*512, bk + l*512, bv + l*512, bs + l*512, qkv, skipb, nullptr, nullptr);
    attn_k<<<rowBlocks, 256, 0, stream>>>(qkv, skipb, x0, rowstart, csrc, xbuf, xb, N);
  }

  // LN1 -> h (f32, in skip) + hb (bf16, in xb)
  ln_k<0><<<rowBlocks, 256, 0, stream>>>(xbuf, lng, lnb, skip, xb, nullptr, N);
  // FFN1: relu(hb @ W1 + b1) -> bf16 t
  gemm8_k<1,512,4><<<MB*4, 512, 0, stream>>>(xb, wt1, N,
      b1, nullptr, nullptr, nullptr, tbuf, nullptr, nullptr, nullptr);
  // FFN2: t @ W2 + b2 + h -> f32 y (in xbuf)
  gemm8_k<2,1024,2><<<MB*2, 512, 0, stream>>>(tbuf, wt2, N,
      b2, nullptr, nullptr, nullptr, nullptr, nullptr, xbuf, skip);
  // LN2 + enc -> d_out
  ln_k<1><<<rowBlocks, 256, 0, stream>>>(xbuf, lng, lnb, (float*)d_out, nullptr, x0, N);
}

// Round 5
// 552.146 us; speedup vs baseline: 1.3096x; 1.3096x over previous
//
#include <hip/hip_runtime.h>

typedef __attribute__((ext_vector_type(8))) short short8;
typedef __attribute__((ext_vector_type(4))) float f32x4;

__device__ __forceinline__ unsigned short f2b(float f){
  union { float f; unsigned u; } x; x.f = f;
  unsigned r = x.u + 0x7fffu + ((x.u >> 16) & 1u);
  return (unsigned short)(r >> 16);
}
__device__ __forceinline__ float b2f(unsigned short v){
  union { unsigned u; float f; } x; x.u = ((unsigned)v) << 16; return x.f;
}

// ---- fp8 e4m3 encode/decode (HW cvt if available) ----
__device__ __forceinline__ unsigned char enc1(float v){
#if __has_builtin(__builtin_amdgcn_cvt_pk_fp8_f32)
  return (unsigned char)(__builtin_amdgcn_cvt_pk_fp8_f32(v, v, 0, false) & 0xff);
#else
  union{float f;unsigned u;}x; x.f=v;
  unsigned s = x.u >> 31;
  float av = fabsf(v);
  if (av >= 448.f) return (unsigned char)((s<<7)|0x7e);
  if (av < 0.0078125f){ unsigned d=(unsigned)(av*512.f+0.5f); return (unsigned char)((s<<7)|d); }
  unsigned q = x.u & 0x7fffffff;
  q = q + 0x7ffff + ((q>>20)&1);
  int e2 = (int)(q>>23) - 127;
  unsigned m3 = (q>>20)&7;
  if (e2 < -6){ unsigned d=(unsigned)(av*512.f+0.5f); return (unsigned char)((s<<7)|d); }
  return (unsigned char)((s<<7) | ((unsigned)(e2+7)<<3) | m3);
#endif
}
__device__ __forceinline__ void dec4(unsigned u, float* o){
#if __has_builtin(__builtin_amdgcn_cvt_pk_f32_fp8)
  auto lo = __builtin_amdgcn_cvt_pk_f32_fp8((int)u, false);
  auto hi = __builtin_amdgcn_cvt_pk_f32_fp8((int)u, true);
  o[0]=lo[0]; o[1]=lo[1]; o[2]=hi[0]; o[3]=hi[1];
#else
  #pragma unroll
  for (int j=0;j<4;j++){
    unsigned b = (u >> (8*j)) & 0xffu;
    unsigned s = b >> 7, ex = (b >> 3) & 15u, mn = b & 7u;
    union{unsigned u;float f;} x;
    x.u = ex ? ((s<<31)|((ex+120u)<<23)|(mn<<20)) : (s<<31);
    o[j] = x.f;
  }
#endif
}

// ---------------- CSR build ----------------
__global__ void count_k(const int* __restrict__ dst, int* __restrict__ deg, int E){
  int e = blockIdx.x*256 + threadIdx.x;
  if (e < E) atomicAdd(&deg[dst[e]], 1);
}

__global__ void scan_k(const int* __restrict__ deg, int* __restrict__ rowstart,
                       int* __restrict__ cursor, int n)
{
  __shared__ int wsum[16];
  int tid = threadIdx.x, lane = tid & 63, wv = tid >> 6;
  int CH = (n + 1023) >> 10;
  int b0 = tid * CH; if (b0 > n) b0 = n;
  int bend = b0 + CH; if (bend > n) bend = n;
  int sum = 0;
  for (int i = b0; i < bend; ++i) sum += deg[i];
  int xs = sum;
  #pragma unroll
  for (int o=1;o<64;o<<=1){ int t = __shfl_up(xs, o, 64); if (lane >= o) xs += t; }
  if (lane == 63) wsum[wv] = xs;
  __syncthreads();
  if (tid < 16){
    int w = wsum[tid];
    #pragma unroll
    for (int o=1;o<16;o<<=1){ int t = __shfl_up(w, o, 64); if (tid >= o) w += t; }
    wsum[tid] = w;
  }
  __syncthreads();
  int off = (wv ? wsum[wv-1] : 0) + xs - sum;
  int run = off;
  for (int i = b0; i < bend; ++i){ rowstart[i] = run; cursor[i] = run; run += deg[i]; }
  if (b0 < n && bend == n) rowstart[n] = run;
  if (n == 0 && tid == 0) rowstart[0] = 0;
}

__global__ void fill_k(const int* __restrict__ src, const int* __restrict__ dst,
                       int* __restrict__ cursor, int* __restrict__ csrc, int E){
  int e = blockIdx.x*256 + threadIdx.x;
  if (e < E){
    int p = atomicAdd(&cursor[dst[e]], 1);
    csrc[p] = src[e];
  }
}

// ---------------- fused weight transposes: Wt[o][i] = W[i][o], bf16 ----------------
__global__ void transpose_all_k(const float* __restrict__ Wq, const float* __restrict__ Wk,
  const float* __restrict__ Wv, const float* __restrict__ Ws,
  const float* __restrict__ W1, const float* __restrict__ W2,
  unsigned short* __restrict__ wtqkvs, unsigned short* __restrict__ wt1,
  unsigned short* __restrict__ wt2)
{
  int bid = blockIdx.x;
  const float* src; unsigned short* dst; int r, c, lb;
  if (bid < 1024){
    int j = bid >> 7;        // 0..7
    int l = j >> 2, w = j & 3;
    src = (w==0?Wq : w==1?Wk : w==2?Wv : Ws) + (size_t)l*512*512;
    dst = wtqkvs + (size_t)l*2048*512 + (size_t)w*512*512;
    r = 512; c = 512; lb = bid & 127;
  } else if (bid < 1280){ src = W1; dst = wt1; r = 512; c = 1024; lb = bid - 1024; }
  else { src = W2; dst = wt2; r = 1024; c = 512; lb = bid - 1280; }
  int idx = lb*256 + threadIdx.x;
  int o = idx % c;
  int i0 = (idx / c) << 3;
  short8 vv;
  #pragma unroll
  for (int j=0;j<8;j++) ((unsigned short*)&vv)[j] = f2b(src[(size_t)(i0+j)*c + o]);
  *(short8*)&dst[(size_t)o*r + i0] = vv;
}

// ---------------- f32 -> bf16 convert (two dests) ----------------
__global__ void cvt2_k(const float* __restrict__ in, unsigned short* __restrict__ out1,
                       unsigned short* __restrict__ out2, size_t n){
  size_t i = ((size_t)blockIdx.x*256 + threadIdx.x)*8;
  if (i >= n) return;
  const float4* p = (const float4*)(in + i);
  float4 a0 = p[0], a1 = p[1];
  short8 vv;
  ((unsigned short*)&vv)[0] = f2b(a0.x); ((unsigned short*)&vv)[1] = f2b(a0.y);
  ((unsigned short*)&vv)[2] = f2b(a0.z); ((unsigned short*)&vv)[3] = f2b(a0.w);
  ((unsigned short*)&vv)[4] = f2b(a1.x); ((unsigned short*)&vv)[5] = f2b(a1.y);
  ((unsigned short*)&vv)[6] = f2b(a1.z); ((unsigned short*)&vv)[7] = f2b(a1.w);
  *(short8*)&out1[i] = vv;
  *(short8*)&out2[i] = vv;
}

// ---------------- GEMM: A[M][KC] bf16 x Bt[NN*128][KC] bf16, depth-2 pipeline ----------------
// MODE 0: QKVS (col<512: bf16 Q->outB[row][512]; 512..1535: fp8 KV->outC[row][1024];
//               >=1536: bf16 S->outB2[row][512])
// MODE 1: FFN1  (bias + relu -> bf16 outB[row][NN*128])
// MODE 2: FFN2  (bias + res  -> f32 outF[row][512])
template<int MODE, int KC, int NN>
__global__ __launch_bounds__(256) void gemm_k(
    const unsigned short* __restrict__ A,
    const unsigned short* __restrict__ Bt,
    int M,
    const float* __restrict__ bias0, const float* __restrict__ bias1,
    const float* __restrict__ bias2, const float* __restrict__ bias3,
    unsigned short* __restrict__ outB, unsigned short* __restrict__ outB2,
    unsigned char* __restrict__ outC,
    float* __restrict__ outF, const float* __restrict__ res)
{
  __shared__ unsigned short lA[2][128*64];
  __shared__ unsigned short lB[2][128*64];
  const int tid  = threadIdx.x;
  const int lane = tid & 63;
  const int wid  = tid >> 6;

  // bijective XCD-chunked swizzle (m204)
  const int nwg = gridDim.x;
  int id = blockIdx.x;
  int q = nwg >> 3, r = nwg & 7;
  int xc = id & 7, yy = id >> 3;
  int swz = (xc < r ? xc*(q+1) : r*(q+1) + (xc-r)*q) + yy;
  const int bm = (swz / NN) * 128;
  const int bn = (swz % NN) * 128;
  const int wm = (wid >> 1) * 64;
  const int wn = (wid & 1) * 64;

  f32x4 acc[4][4];
  #pragma unroll
  for (int m=0;m<4;m++)
    #pragma unroll
    for (int n=0;n<4;n++) acc[m][n] = (f32x4)0.f;

  constexpr int NT = KC / 64;

  auto STAGE = [&](int buf, int kt){
    #pragma unroll
    for (int it = 0; it < 4; ++it) {
      int chunk = it*256 + tid;
      int row = chunk >> 3;
      int cin = chunk & 7;
      int scol = (cin ^ (row & 7)) * 8;   // pre-swizzled global source (rule 21)
      int ga = bm + row; if (ga >= M) ga = M - 1;
      __builtin_amdgcn_global_load_lds(
        (const __attribute__((address_space(1))) void*)(A + (size_t)ga * KC + kt + scol),
        (__attribute__((address_space(3))) void*)(&lA[buf][(it*256 + (wid<<6)) * 8]),
        16, 0, 0);
      __builtin_amdgcn_global_load_lds(
        (const __attribute__((address_space(1))) void*)(Bt + (size_t)(bn + row) * KC + kt + scol),
        (__attribute__((address_space(3))) void*)(&lB[buf][(it*256 + (wid<<6)) * 8]),
        16, 0, 0);
    }
  };

  auto COMPUTE = [&](int buf){
    #pragma unroll
    for (int ks = 0; ks < 2; ++ks) {
      short8 af[4], bfr[4];
      #pragma unroll
      for (int m=0;m<4;m++){
        int rr = wm + m*16 + (lane & 15);
        int ch = (ks*4 + (lane >> 4)) ^ (rr & 7);
        af[m] = *(const short8*)&lA[buf][rr*64 + ch*8];
      }
      #pragma unroll
      for (int n=0;n<4;n++){
        int rr = wn + n*16 + (lane & 15);
        int ch = (ks*4 + (lane >> 4)) ^ (rr & 7);
        bfr[n] = *(const short8*)&lB[buf][rr*64 + ch*8];
      }
      #pragma unroll
      for (int m=0;m<4;m++)
        #pragma unroll
        for (int n=0;n<4;n++)
          acc[m][n] = __builtin_amdgcn_mfma_f32_16x16x32_bf16(af[m], bfr[n], acc[m][n], 0,0,0);
    }
  };

  STAGE(0, 0);
  if (NT > 1) STAGE(1, 64);
  #pragma unroll
  for (int t = 0; t < NT; ++t){
    if (t == NT-1) asm volatile("s_waitcnt vmcnt(0)" ::: "memory");
    else           asm volatile("s_waitcnt vmcnt(8)" ::: "memory");
    __builtin_amdgcn_s_barrier();
    COMPUTE(t & 1);
    asm volatile("s_waitcnt lgkmcnt(0)" ::: "memory");
    __builtin_amdgcn_s_barrier();
    if (t + 2 < NT) STAGE(t & 1, (t+2)*64);
  }

  #pragma unroll
  for (int m=0;m<4;m++){
    int row0 = bm + wm + m*16 + ((lane >> 4) << 2);
    #pragma unroll
    for (int n=0;n<4;n++){
      int col = bn + wn + n*16 + (lane & 15);
      float bval;
      if (MODE == 0){
        bval = (col < 512) ? bias0[col]
             : (col < 1024) ? bias1[col-512]
             : (col < 1536) ? bias2[col-1024] : bias3[col-1536];
      } else {
        bval = bias0[col];
      }
      #pragma unroll
      for (int r4=0;r4<4;r4++){
        int row = row0 + r4;
        if (row < M){
          float v = acc[m][n][r4] + bval;
          if (MODE == 0){
            if (col < 512)       outB[(size_t)row*512 + col] = f2b(v);
            else if (col < 1536) outC[(size_t)row*1024 + (col-512)] = enc1(v);
            else                 outB2[(size_t)row*512 + (col-1536)] = f2b(v);
          } else if (MODE == 1){
            v = fmaxf(v, 0.0f);
            outB[(size_t)row*(NN*128) + col] = f2b(v);
          } else {
            v += res[(size_t)row*512 + col];
            outF[(size_t)row*512 + col] = v;
          }
        }
      }
    }
  }
}

// ---------------- attention: one wave per destination node, online softmax ----------------
// K/V in fp8 e4m3 (halves gather traffic); prefetch next edge's K/V.
template<int WF32>
__global__ __launch_bounds__(256) void attn_k(
  const unsigned short* __restrict__ qb, const unsigned char* __restrict__ kv8,
  const unsigned short* __restrict__ skipb, const unsigned short* __restrict__ encb,
  const int* __restrict__ rowstart, const int* __restrict__ csrc,
  float* __restrict__ xout, unsigned short* __restrict__ xoutb, int N)
{
  int n = blockIdx.x*4 + (threadIdx.x>>6);
  if (n >= N) return;
  int lane = threadIdx.x & 63;
  const short8 qv = *(const short8*)&qb[(size_t)n*512 + lane*8];
  float qf[8];
  #pragma unroll
  for (int j=0;j<8;j++) qf[j] = b2f(((const unsigned short*)&qv)[j]);
  float m = -__builtin_inff(), l = 0.f;
  float acc[8] = {0.f,0.f,0.f,0.f,0.f,0.f,0.f,0.f};
  int e = rowstart[n], e1 = rowstart[n+1];
  if (e < e1){
    int s = csrc[e];
    uint2 kc = *(const uint2*)&kv8[(size_t)s*1024 + lane*8];
    uint2 vc = *(const uint2*)&kv8[(size_t)s*1024 + 512 + lane*8];
    for (; e < e1; ++e){
      int sn = (e+1 < e1) ? csrc[e+1] : s;
      uint2 kn = *(const uint2*)&kv8[(size_t)sn*1024 + lane*8];
      uint2 vn = *(const uint2*)&kv8[(size_t)sn*1024 + 512 + lane*8];
      float kf[8]; dec4(kc.x, kf); dec4(kc.y, kf+4);
      float dot = 0.f;
      #pragma unroll
      for (int j=0;j<8;j++) dot += qf[j]*kf[j];
      dot += __shfl_xor(dot,1); dot += __shfl_xor(dot,2); dot += __shfl_xor(dot,4);
      float a = dot * 0.125f;               // 1/sqrt(64)
      float mn2 = fmaxf(m, a);
      float corr = __expf(m - mn2);
      float p = __expf(a - mn2);
      l = l*corr + p;
      float vf[8]; dec4(vc.x, vf); dec4(vc.y, vf+4);
      #pragma unroll
      for (int j=0;j<8;j++) acc[j] = acc[j]*corr + p*vf[j];
      m = mn2;
      kc = kn; vc = vn;
    }
  }
  float inv = 1.f/(l + 1e-16f);
  size_t base = (size_t)n*512 + (size_t)lane*8;
  const short8 sv = *(const short8*)&skipb[base];
  const short8 ev = *(const short8*)&encb[base];
  short8 ob;
  #pragma unroll
  for (int j=0;j<8;j++){
    float o = acc[j]*inv + b2f(((const unsigned short*)&sv)[j]) + b2f(((const unsigned short*)&ev)[j]);
    if (WF32) xout[base+j] = o;
    ((unsigned short*)&ob)[j] = f2b(o);
  }
  *(short8*)&xoutb[base] = ob;
}

// ---------------- LayerNorm (wave per row) ----------------
template<int MODE>
__global__ __launch_bounds__(256) void ln_k(const float* __restrict__ x,
  const float* __restrict__ g, const float* __restrict__ b,
  float* __restrict__ outF, unsigned short* __restrict__ outB,
  const float* __restrict__ addv, int N)
{
  int n = blockIdx.x*4 + (threadIdx.x>>6);
  if (n >= N) return;
  int lane = threadIdx.x & 63;
  size_t base = (size_t)n*512 + (size_t)lane*8;
  const float4* p = (const float4*)(x + base);
  float4 a0 = p[0], a1 = p[1];
  float v[8] = {a0.x,a0.y,a0.z,a0.w,a1.x,a1.y,a1.z,a1.w};
  float s=0.f, ss=0.f;
  #pragma unroll
  for (int j=0;j<8;j++){ s += v[j]; ss += v[j]*v[j]; }
  #pragma unroll
  for (int o=1;o<64;o<<=1){ s += __shfl_xor(s,o); ss += __shfl_xor(ss,o); }
  float mean = s * (1.f/512.f);
  float var  = ss * (1.f/512.f) - mean*mean;
  float rstd = rsqrtf(var + 1e-5f);
  #pragma unroll
  for (int j=0;j<8;j++){
    int c = lane*8 + j;
    float o = (v[j]-mean)*rstd*g[c] + b[c];
    if (MODE == 0){ outF[base+j] = o; outB[base+j] = f2b(o); }
    else          { outF[base+j] = o + addv[base+j]; }
  }
}

extern "C" void kernel_launch(void* const* d_in, const int* in_sizes, int n_in,
                              void* d_out, int out_size, void* d_ws, size_t ws_size,
                              hipStream_t stream)
{
  const float* x0  = (const float*)d_in[0];
  const int*  eidx = (const int*)d_in[1];
  const float* Wq  = (const float*)d_in[4];
  const float* bq  = (const float*)d_in[5];
  const float* Wk  = (const float*)d_in[6];
  const float* bk  = (const float*)d_in[7];
  const float* Wv  = (const float*)d_in[8];
  const float* bv  = (const float*)d_in[9];
  const float* Wsk = (const float*)d_in[10];
  const float* bs  = (const float*)d_in[11];
  const float* W1  = (const float*)d_in[12];
  const float* b1  = (const float*)d_in[13];
  const float* W2  = (const float*)d_in[14];
  const float* b2  = (const float*)d_in[15];
  const float* lng = (const float*)d_in[16];
  const float* lnb = (const float*)d_in[17];

  const int N = in_sizes[0] / 512;
  const int E = in_sizes[1] / 2;
  const int* esrc = eidx;
  const int* edst = eidx + E;

  char* ws = (char*)d_ws;
  size_t off = 0;
  auto alloc = [&](size_t bytes)->char*{
    char* p = ws + off; off = (off + bytes + 255) & ~(size_t)255; return p;
  };
  unsigned short* wtqkvs = (unsigned short*)alloc((size_t)2*2048*512*2);
  unsigned short* wt1    = (unsigned short*)alloc((size_t)1024*512*2);
  unsigned short* wt2    = (unsigned short*)alloc((size_t)512*1024*2);
  unsigned short* qb     = (unsigned short*)alloc((size_t)N*512*2);  // Q bf16
  unsigned char*  kv8    = (unsigned char*)alloc((size_t)N*1024);    // K,V fp8 (contig after qb)
  float*          skip   = (float*)alloc((size_t)N*512*4);           // f32 h after LN1
  float*          xbuf   = (float*)alloc((size_t)N*512*4);
  unsigned short* xb     = (unsigned short*)alloc((size_t)N*512*2);  // bf16 x / hb
  unsigned short* encb   = (unsigned short*)alloc((size_t)N*512*2);  // bf16 enc
  unsigned short* skipb  = (unsigned short*)alloc((size_t)N*512*2);  // bf16 skip proj
  int* deg      = (int*)alloc((size_t)N*4);
  int* rowstart = (int*)alloc((size_t)(N+1)*4);
  int* cursor   = (int*)alloc((size_t)N*4);
  int* csrc     = (int*)alloc((size_t)E*4);
  unsigned short* tbuf = qb;  // alias: qb+kv8 = N*2048 bytes = N*1024 bf16, dead by FFN time

  // CSR build
  hipMemsetAsync(deg, 0, (size_t)N*4, stream);
  count_k<<<(E+255)/256, 256, 0, stream>>>(edst, deg, E);
  scan_k<<<1, 1024, 0, stream>>>(deg, rowstart, cursor, N);
  fill_k<<<(E+255)/256, 256, 0, stream>>>(esrc, edst, cursor, csrc, E);

  // all weight transposes in one launch
  transpose_all_k<<<1536, 256, 0, stream>>>(Wq, Wk, Wv, Wsk, W1, W2, wtqkvs, wt1, wt2);

  const int cvtBlocks = (int)(((size_t)N*512/8 + 255)/256);
  const int rowBlocks = (N + 3)/4;
  const int MB = (N + 127)/128;   // 157

  // 2 TransformerConv layers
  cvt2_k<<<cvtBlocks, 256, 0, stream>>>(x0, xb, encb, (size_t)N*512);
  for (int l = 0; l < 2; ++l){
    gemm_k<0,512,16><<<MB*16, 256, 0, stream>>>(xb, wtqkvs + (size_t)l*2048*512, N,
        bq + l*512, bk + l*512, bv + l*512, bs + l*512, qb, skipb, kv8, nullptr, nullptr);
    if (l == 0)
      attn_k<0><<<rowBlocks, 256, 0, stream>>>(qb, kv8, skipb, encb, rowstart, csrc, nullptr, xb, N);
    else
      attn_k<1><<<rowBlocks, 256, 0, stream>>>(qb, kv8, skipb, encb, rowstart, csrc, xbuf, xb, N);
  }

  // LN1 -> h (f32, in skip) + hb (bf16, in xb)
  ln_k<0><<<rowBlocks, 256, 0, stream>>>(xbuf, lng, lnb, skip, xb, nullptr, N);
  // FFN1: relu(hb @ W1 + b1) -> bf16 t
  gemm_k<1,512,8><<<MB*8, 256, 0, stream>>>(xb, wt1, N,
      b1, nullptr, nullptr, nullptr, tbuf, nullptr, nullptr, nullptr, nullptr);
  // FFN2: t @ W2 + b2 + h -> f32 y (in xbuf)
  gemm_k<2,1024,4><<<MB*4, 256, 0, stream>>>(tbuf, wt2, N,
      b2, nullptr, nullptr, nullptr, nullptr, nullptr, nullptr, xbuf, skip);
  // LN2 + enc -> d_out
  ln_k<1><<<rowBlocks, 256, 0, stream>>>(xbuf, lng, lnb, (float*)d_out, nullptr, x0, N);
}